// Round 1
// baseline (2942.613 us; speedup 1.0000x reference)
//
#include <hip/hip_runtime.h>
#include <math.h>

// ---------------------------------------------------------------------------
// GCN forward: 2-layer, N=100000 nodes (512->16->40), E=3.2M edges + self loops
// Pipeline:
//   1) detect edge_index dtype (int64 vs int32) on device
//   2) deg[i] = 1 + count(row==i); dinv = rsqrt(deg)
//   3) h = x @ W1  (fused: agg1 = h*dinv^2  -- the self-loop term)
//   4) edge pass 1: agg1[row] += h[col]*dinv[row]*dinv[col]   (atomics)
//   5) h2 = relu(agg1+b1) @ W2 (fused: agg2 = h2*dinv^2), agg2 lives in d_out
//   6) edge pass 2: agg2[row] += h2[col]*norm                 (atomics)
//   7) out = log_softmax(agg2 + b2) rowwise, in-place in d_out
// ---------------------------------------------------------------------------

__global__ void k_detect(const int* __restrict__ ei32, int* __restrict__ flag) {
    // If edge_index is int64 (values < 2^31), every odd int32 word is 0.
    int t = threadIdx.x;
    bool z = (ei32[2 * t + 1] == 0);
    unsigned long long m = __ballot(z);
    if (t == 0) *flag = (m == 0xFFFFFFFFFFFFFFFFULL) ? 1 : 0;
}

__global__ void k_initdeg(float* __restrict__ deg, int n) {
    int i = blockIdx.x * blockDim.x + threadIdx.x;
    if (i < n) deg[i] = 1.0f;  // self-loop
}

__global__ void k_count(const void* __restrict__ ei, const int* __restrict__ flag,
                        float* __restrict__ deg, int E) {
    int e = blockIdx.x * blockDim.x + threadIdx.x;
    if (e >= E) return;
    int r;
    if (*flag) r = (int)((const long long*)ei)[e];
    else       r = ((const int*)ei)[e];
    atomicAdd(&deg[r], 1.0f);
}

__global__ void k_rsqrt(float* __restrict__ deg, int n) {
    int i = blockIdx.x * blockDim.x + threadIdx.x;
    if (i < n) deg[i] = rsqrtf(deg[i]);  // deg >= 1 always (self-loop)
}

// ---------------------------------------------------------------------------
// GEMM1: h[100000x16] = x[100000x512] @ W1[512x16]
// 16 rows per block, 256 threads = (r=tid>>4, c=tid&15).
// x tile and W1^T staged in LDS (exactly 64KB), XOR-swizzled at float4
// granularity to avoid bank conflicts.
// ---------------------------------------------------------------------------
__global__ __launch_bounds__(256) void k_gemm1(
        const float* __restrict__ x, const float* __restrict__ W1,
        const float* __restrict__ dinv, float* __restrict__ h,
        float* __restrict__ agg1, int n) {
    __shared__ float xs[16 * 512];
    __shared__ float wt[16 * 512];
    const int tid = threadIdx.x;
    const int rbase = blockIdx.x * 16;

    // stage W1 (512x16 row-major) transposed into wt[c][k], swizzled quads
    for (int k = tid; k < 512; k += 256) {
        const float4* wrow = (const float4*)(W1 + k * 16);
        int kq = k >> 2, kl = k & 3;
        #pragma unroll
        for (int j = 0; j < 4; ++j) {
            float4 vv = wrow[j];
            int c0 = 4 * j;
            wt[(c0 + 0) * 512 + ((kq ^ ((c0 + 0) & 7)) << 2) + kl] = vv.x;
            wt[(c0 + 1) * 512 + ((kq ^ ((c0 + 1) & 7)) << 2) + kl] = vv.y;
            wt[(c0 + 2) * 512 + ((kq ^ ((c0 + 2) & 7)) << 2) + kl] = vv.z;
            wt[(c0 + 3) * 512 + ((kq ^ ((c0 + 3) & 7)) << 2) + kl] = vv.w;
        }
    }
    // stage 16 rows of x, swizzled
    const float4* x4 = (const float4*)(x + (size_t)rbase * 512);
    #pragma unroll
    for (int i = 0; i < 8; ++i) {
        int idx = tid + 256 * i;      // float4 index within the 16x512 tile
        int row = idx >> 7;           // 0..15
        int kq = idx & 127;
        float4 v;
        if (rbase + row < n) v = x4[idx];
        else                 v = make_float4(0.f, 0.f, 0.f, 0.f);
        ((float4*)xs)[row * 128 + (kq ^ (row & 7))] = v;
    }
    __syncthreads();

    const int r = tid >> 4, c = tid & 15;
    const float4* xr = ((const float4*)xs) + r * 128;
    const float4* wr = ((const float4*)wt) + c * 128;
    const int rx = r & 7, cx = c & 7;
    float acc = 0.f;
    #pragma unroll 8
    for (int kq = 0; kq < 128; ++kq) {
        float4 a = xr[kq ^ rx];
        float4 b = wr[kq ^ cx];
        acc += a.x * b.x + a.y * b.y + a.z * b.z + a.w * b.w;
    }
    int row = rbase + r;
    if (row < n) {
        float d = dinv[row];
        h[row * 16 + c] = acc;
        agg1[row * 16 + c] = acc * d * d;  // self-loop contribution
    }
}

// ---------------------------------------------------------------------------
// Edge pass 1 (F=16): thread per (edge, quad-of-4-features)
// ---------------------------------------------------------------------------
__global__ __launch_bounds__(256) void k_edge1(
        const void* __restrict__ ei, const int* __restrict__ flag,
        const float* __restrict__ dinv, const float* __restrict__ h,
        float* __restrict__ agg1, int E) {
    int tid = blockIdx.x * blockDim.x + threadIdx.x;
    int e = tid >> 2, q = tid & 3;
    if (e >= E) return;
    int r, c;
    if (*flag) { const long long* p = (const long long*)ei; r = (int)p[e]; c = (int)p[E + e]; }
    else       { const int* p = (const int*)ei;             r = p[e];      c = p[E + e]; }
    float nrm = dinv[r] * dinv[c];
    float4 hv = *(const float4*)(h + c * 16 + q * 4);
    float* dst = agg1 + r * 16 + q * 4;
    atomicAdd(dst + 0, hv.x * nrm);
    atomicAdd(dst + 1, hv.y * nrm);
    atomicAdd(dst + 2, hv.z * nrm);
    atomicAdd(dst + 3, hv.w * nrm);
}

// ---------------------------------------------------------------------------
// Layer 2 row kernel: v = relu(agg1+b1); h2 = v@W2; agg2 = h2*dinv^2
// W2 (16x40) broadcast from LDS -- all lanes read the same address (no
// conflicts). One row per thread.
// ---------------------------------------------------------------------------
__global__ __launch_bounds__(256) void k_layer2(
        const float* __restrict__ agg1, const float* __restrict__ W2,
        const float* __restrict__ b1, const float* __restrict__ dinv,
        float* __restrict__ h2, float* __restrict__ agg2, int n) {
    __shared__ float w2s[640];
    __shared__ float b1s[16];
    int tid = threadIdx.x;
    if (tid < 160) ((float4*)w2s)[tid] = ((const float4*)W2)[tid];
    if (tid < 16)  b1s[tid] = b1[tid];
    __syncthreads();
    int i = blockIdx.x * 256 + tid;
    if (i >= n) return;

    float v[16];
    const float4* a4 = (const float4*)(agg1 + i * 16);
    #pragma unroll
    for (int j = 0; j < 4; ++j) {
        float4 t = a4[j];
        v[4 * j + 0] = fmaxf(t.x + b1s[4 * j + 0], 0.f);
        v[4 * j + 1] = fmaxf(t.y + b1s[4 * j + 1], 0.f);
        v[4 * j + 2] = fmaxf(t.z + b1s[4 * j + 2], 0.f);
        v[4 * j + 3] = fmaxf(t.w + b1s[4 * j + 3], 0.f);
    }
    float4 acc[10];
    #pragma unroll
    for (int j = 0; j < 10; ++j) acc[j] = make_float4(0.f, 0.f, 0.f, 0.f);
    #pragma unroll
    for (int k = 0; k < 16; ++k) {
        float vk = v[k];
        const float4* wrow = (const float4*)(w2s + k * 40);
        #pragma unroll
        for (int j = 0; j < 10; ++j) {
            float4 w = wrow[j];
            acc[j].x += vk * w.x; acc[j].y += vk * w.y;
            acc[j].z += vk * w.z; acc[j].w += vk * w.w;
        }
    }
    float d = dinv[i], d2 = d * d;
    float4* h2o = (float4*)(h2 + i * 40);
    float4* ago = (float4*)(agg2 + i * 40);
    #pragma unroll
    for (int j = 0; j < 10; ++j) {
        float4 t = acc[j];
        h2o[j] = t;
        ago[j] = make_float4(t.x * d2, t.y * d2, t.z * d2, t.w * d2);
    }
}

// ---------------------------------------------------------------------------
// Edge pass 2 (F=40): thread per (edge, quad) -- 10 quads per edge
// ---------------------------------------------------------------------------
__global__ __launch_bounds__(256) void k_edge2(
        const void* __restrict__ ei, const int* __restrict__ flag,
        const float* __restrict__ dinv, const float* __restrict__ h2,
        float* __restrict__ agg2, int E) {
    int tid = blockIdx.x * blockDim.x + threadIdx.x;
    int e = tid / 10, q = tid - e * 10;
    if (e >= E) return;
    int r, c;
    if (*flag) { const long long* p = (const long long*)ei; r = (int)p[e]; c = (int)p[E + e]; }
    else       { const int* p = (const int*)ei;             r = p[e];      c = p[E + e]; }
    float nrm = dinv[r] * dinv[c];
    float4 hv = *(const float4*)(h2 + c * 40 + q * 4);
    float* dst = agg2 + r * 40 + q * 4;
    atomicAdd(dst + 0, hv.x * nrm);
    atomicAdd(dst + 1, hv.y * nrm);
    atomicAdd(dst + 2, hv.z * nrm);
    atomicAdd(dst + 3, hv.w * nrm);
}

// ---------------------------------------------------------------------------
// log_softmax rowwise, in-place (agg2 == out)
// ---------------------------------------------------------------------------
__global__ __launch_bounds__(256) void k_lsm(
        const float* __restrict__ agg2, const float* __restrict__ b2,
        float* __restrict__ out, int n) {
    __shared__ float b2s[40];
    int tid = threadIdx.x;
    if (tid < 40) b2s[tid] = b2[tid];
    __syncthreads();
    int i = blockIdx.x * 256 + tid;
    if (i >= n) return;
    float v[40];
    const float4* a4 = (const float4*)(agg2 + i * 40);
    #pragma unroll
    for (int j = 0; j < 10; ++j) {
        float4 t = a4[j];
        v[4 * j + 0] = t.x + b2s[4 * j + 0];
        v[4 * j + 1] = t.y + b2s[4 * j + 1];
        v[4 * j + 2] = t.z + b2s[4 * j + 2];
        v[4 * j + 3] = t.w + b2s[4 * j + 3];
    }
    float m = v[0];
    #pragma unroll
    for (int k = 1; k < 40; ++k) m = fmaxf(m, v[k]);
    float s = 0.f;
    #pragma unroll
    for (int k = 0; k < 40; ++k) s += __expf(v[k] - m);
    float ls = __logf(s) + m;
    float4* o4 = (float4*)(out + i * 40);
    #pragma unroll
    for (int j = 0; j < 10; ++j)
        o4[j] = make_float4(v[4 * j + 0] - ls, v[4 * j + 1] - ls,
                            v[4 * j + 2] - ls, v[4 * j + 3] - ls);
}

extern "C" void kernel_launch(void* const* d_in, const int* in_sizes, int n_in,
                              void* d_out, int out_size, void* d_ws, size_t ws_size,
                              hipStream_t stream) {
    const float* x  = (const float*)d_in[0];
    const void*  ei = d_in[1];
    const float* W1 = (const float*)d_in[2];
    const float* b1 = (const float*)d_in[3];
    const float* W2 = (const float*)d_in[4];
    const float* b2 = (const float*)d_in[5];
    float* out = (float*)d_out;

    const int n = in_sizes[0] / 512;
    const int E = in_sizes[1] / 2;

    // workspace layout (all 16B aligned): flag | deg/dinv[n] | h[n*16] | agg1[n*16] | h2[n*40]
    char* w = (char*)d_ws;
    int*   flag = (int*)w;
    float* deg  = (float*)(w + 256);            // becomes dinv after k_rsqrt
    float* h    = deg + n;
    float* agg1 = h + (size_t)n * 16;
    float* h2   = agg1 + (size_t)n * 16;
    float* agg2 = out;                          // agg2 lives in d_out

    const int nb = (n + 255) / 256;
    k_detect<<<1, 64, 0, stream>>>((const int*)ei, flag);
    k_initdeg<<<nb, 256, 0, stream>>>(deg, n);
    k_count<<<(E + 255) / 256, 256, 0, stream>>>(ei, flag, deg, E);
    k_rsqrt<<<nb, 256, 0, stream>>>(deg, n);
    k_gemm1<<<(n + 15) / 16, 256, 0, stream>>>(x, W1, deg, h, agg1, n);
    k_edge1<<<(E * 4 + 255) / 256, 256, 0, stream>>>(ei, flag, deg, h, agg1, E);
    k_layer2<<<nb, 256, 0, stream>>>(agg1, W2, b1, deg, h2, agg2, n);
    k_edge2<<<(E * 10 + 255) / 256, 256, 0, stream>>>(ei, flag, deg, h2, agg2, E);
    k_lsm<<<nb, 256, 0, stream>>>(agg2, b2, out, n);
}

// Round 2
// 795.360 us; speedup vs baseline: 3.6997x; 3.6997x over previous
//
#include <hip/hip_runtime.h>
#include <math.h>

// ---------------------------------------------------------------------------
// GCN forward, CSR-based (no feature-space atomics):
//   1) detect edge_index dtype (int64 vs int32)
//   2) deg count (int atomics), dinv = rsqrt(1+deg)
//   3) row_ptr = exclusive scan(deg) (3-kernel scan); scatter cols -> CSR
//   4) hn = (x @ W1) * dinv          [thread-per-row, W1 in LDS broadcast]
//   5) agg1[i] = dinv[i]*(hn[i] + sum_{e:row=i} hn[col])   [wave-per-node]
//   6) h2n = relu(agg1+b1) @ W2 * dinv
//   7) out[i] = log_softmax(dinv[i]*(h2n[i]+sum hn2[col]) + b2)  [fused]
// Key algebra: norm = dinv[r]*dinv[c]  =>  pre-scale features by dinv[c] once,
// post-scale row sums by dinv[r]; no per-edge norm storage, no dinv gathers.
// ---------------------------------------------------------------------------

#define CHUNK 1024

__global__ void k_detect(const int* __restrict__ ei32, int* __restrict__ flag) {
    int t = threadIdx.x;
    bool z = (ei32[2 * t + 1] == 0);
    unsigned long long m = __ballot(z);
    if (t == 0) *flag = (m == 0xFFFFFFFFFFFFFFFFULL) ? 1 : 0;
}

__global__ void k_zero(int* __restrict__ p, int n) {
    int i = blockIdx.x * blockDim.x + threadIdx.x;
    if (i < n) p[i] = 0;
}

__global__ void k_count(const void* __restrict__ ei, const int* __restrict__ flag,
                        int* __restrict__ deg, int E) {
    int e = blockIdx.x * blockDim.x + threadIdx.x;
    if (e >= E) return;
    int r;
    if (*flag) r = (int)((const long long*)ei)[e];
    else       r = ((const int*)ei)[e];
    atomicAdd(&deg[r], 1);
}

__global__ void k_dinv(const int* __restrict__ deg, float* __restrict__ dinv, int n) {
    int i = blockIdx.x * blockDim.x + threadIdx.x;
    if (i < n) dinv[i] = rsqrtf(1.0f + (float)deg[i]);  // +1 = self-loop
}

// ---- 3-kernel exclusive scan of deg -> row_ptr (and cursor copy) ----
__global__ void k_chunksum(const int* __restrict__ deg, int* __restrict__ csum, int n) {
    __shared__ int ls[256];
    int tid = threadIdx.x;
    int base = blockIdx.x * CHUNK + tid * 4;
    int s = 0;
    #pragma unroll
    for (int t = 0; t < 4; ++t) { int idx = base + t; if (idx < n) s += deg[idx]; }
    ls[tid] = s; __syncthreads();
    for (int off = 128; off > 0; off >>= 1) {
        if (tid < off) ls[tid] += ls[tid + off];
        __syncthreads();
    }
    if (tid == 0) csum[blockIdx.x] = ls[0];
}

__global__ void k_scanpart(const int* __restrict__ csum, int* __restrict__ coff,
                           int nch, int* __restrict__ row_ptr, int n, int E) {
    __shared__ int ls[256];
    int tid = threadIdx.x;
    int v = (tid < nch) ? csum[tid] : 0;
    ls[tid] = v; __syncthreads();
    for (int off = 1; off < 256; off <<= 1) {
        int t = (tid >= off) ? ls[tid - off] : 0;
        __syncthreads();
        ls[tid] += t;
        __syncthreads();
    }
    coff[tid] = ls[tid] - v;  // exclusive
    if (tid == 0) row_ptr[n] = E;
}

__global__ void k_scanlocal(const int* __restrict__ deg, const int* __restrict__ coff,
                            int* __restrict__ row_ptr, int* __restrict__ cursor, int n) {
    __shared__ int ls[256];
    int tid = threadIdx.x, b = blockIdx.x;
    int base = b * CHUNK + tid * 4;
    int v[4]; int s = 0;
    #pragma unroll
    for (int t = 0; t < 4; ++t) {
        int idx = base + t;
        v[t] = (idx < n) ? deg[idx] : 0;
        s += v[t];
    }
    ls[tid] = s; __syncthreads();
    for (int off = 1; off < 256; off <<= 1) {
        int t = (tid >= off) ? ls[tid - off] : 0;
        __syncthreads();
        ls[tid] += t;
        __syncthreads();
    }
    int run = ls[tid] - s + coff[b];
    #pragma unroll
    for (int t = 0; t < 4; ++t) {
        int idx = base + t;
        if (idx < n) { row_ptr[idx] = run; cursor[idx] = run; }
        run += v[t];
    }
}

__global__ void k_scatter(const void* __restrict__ ei, const int* __restrict__ flag,
                          int* __restrict__ cursor, int* __restrict__ csr_col, int E) {
    int e = blockIdx.x * blockDim.x + threadIdx.x;
    if (e >= E) return;
    int r, c;
    if (*flag) { const long long* p = (const long long*)ei; r = (int)p[e]; c = (int)p[E + e]; }
    else       { const int* p = (const int*)ei;             r = p[e];      c = p[E + e]; }
    int pos = atomicAdd(&cursor[r], 1);
    csr_col[pos] = c;
}

// ---------------------------------------------------------------------------
// GEMM1: hn[row] = (x[row] @ W1) * dinv[row].  Thread per row; W1 (32KB) in
// LDS, all reads lane-uniform (broadcast, conflict-free).
// ---------------------------------------------------------------------------
__global__ __launch_bounds__(256) void k_gemm1(
        const float* __restrict__ x, const float* __restrict__ W1,
        const float* __restrict__ dinv, float* __restrict__ hn, int n) {
    __shared__ float w1s[512 * 16];
    int tid = threadIdx.x;
    for (int i = tid; i < 2048; i += 256)
        ((float4*)w1s)[i] = ((const float4*)W1)[i];
    __syncthreads();
    int row = blockIdx.x * 256 + tid;
    if (row >= n) return;

    float4 a0 = {0, 0, 0, 0}, a1 = {0, 0, 0, 0}, a2 = {0, 0, 0, 0}, a3 = {0, 0, 0, 0};
    const float4* xr = (const float4*)(x + (size_t)row * 512);
    #pragma unroll 4
    for (int kq = 0; kq < 128; ++kq) {
        float4 xv = xr[kq];
        const float4* w = (const float4*)(w1s + kq * 64);  // 4 k-rows of 16
        #pragma unroll
        for (int j = 0; j < 4; ++j) {
            float xk = (j == 0) ? xv.x : (j == 1) ? xv.y : (j == 2) ? xv.z : xv.w;
            float4 w0 = w[4 * j + 0], w1 = w[4 * j + 1], w2 = w[4 * j + 2], w3 = w[4 * j + 3];
            a0.x += xk * w0.x; a0.y += xk * w0.y; a0.z += xk * w0.z; a0.w += xk * w0.w;
            a1.x += xk * w1.x; a1.y += xk * w1.y; a1.z += xk * w1.z; a1.w += xk * w1.w;
            a2.x += xk * w2.x; a2.y += xk * w2.y; a2.z += xk * w2.z; a2.w += xk * w2.w;
            a3.x += xk * w3.x; a3.y += xk * w3.y; a3.z += xk * w3.z; a3.w += xk * w3.w;
        }
    }
    float d = dinv[row];
    float4* o = (float4*)(hn + (size_t)row * 16);
    o[0] = make_float4(a0.x * d, a0.y * d, a0.z * d, a0.w * d);
    o[1] = make_float4(a1.x * d, a1.y * d, a1.z * d, a1.w * d);
    o[2] = make_float4(a2.x * d, a2.y * d, a2.z * d, a2.w * d);
    o[3] = make_float4(a3.x * d, a3.y * d, a3.z * d, a3.w * d);
}

// ---------------------------------------------------------------------------
// Aggregation layer 1 (F=16): wave per node; 64 lanes = 4 edge-slots x 16 feats
// ---------------------------------------------------------------------------
__global__ __launch_bounds__(256) void k_agg1(
        const float* __restrict__ hn, const int* __restrict__ row_ptr,
        const int* __restrict__ csr_col, const float* __restrict__ dinv,
        float* __restrict__ agg1, int n) {
    int wid = threadIdx.x >> 6, lane = threadIdx.x & 63;
    int i = blockIdx.x * 4 + wid;
    if (i >= n) return;
    int g = lane >> 4, f = lane & 15;
    int start = row_ptr[i], end = row_ptr[i + 1];
    float acc = 0.f;
    int j = start + g;
    int c = (j < end) ? csr_col[j] : 0;
    while (j < end) {
        int jn = j + 4;
        int cn = (jn < end) ? csr_col[jn] : 0;   // prefetch next col
        acc += hn[c * 16 + f];
        c = cn; j = jn;
    }
    acc += __shfl_xor(acc, 16);
    acc += __shfl_xor(acc, 32);
    if (lane < 16) {
        float d = dinv[i];
        agg1[i * 16 + f] = d * (acc + hn[i * 16 + f]);  // + self-loop
    }
}

// ---------------------------------------------------------------------------
// Layer 2: h2n[i] = relu(agg1[i]+b1) @ W2 * dinv[i].  Thread per row.
// ---------------------------------------------------------------------------
__global__ __launch_bounds__(256) void k_layer2(
        const float* __restrict__ agg1, const float* __restrict__ W2,
        const float* __restrict__ b1, const float* __restrict__ dinv,
        float* __restrict__ h2n, int n) {
    __shared__ float w2s[640];
    __shared__ float b1s[16];
    int tid = threadIdx.x;
    if (tid < 160) ((float4*)w2s)[tid] = ((const float4*)W2)[tid];
    if (tid < 16)  b1s[tid] = b1[tid];
    __syncthreads();
    int i = blockIdx.x * 256 + tid;
    if (i >= n) return;

    float v[16];
    const float4* a4 = (const float4*)(agg1 + (size_t)i * 16);
    #pragma unroll
    for (int j = 0; j < 4; ++j) {
        float4 t = a4[j];
        v[4 * j + 0] = fmaxf(t.x + b1s[4 * j + 0], 0.f);
        v[4 * j + 1] = fmaxf(t.y + b1s[4 * j + 1], 0.f);
        v[4 * j + 2] = fmaxf(t.z + b1s[4 * j + 2], 0.f);
        v[4 * j + 3] = fmaxf(t.w + b1s[4 * j + 3], 0.f);
    }
    float4 acc[10];
    #pragma unroll
    for (int j = 0; j < 10; ++j) acc[j] = make_float4(0.f, 0.f, 0.f, 0.f);
    #pragma unroll
    for (int k = 0; k < 16; ++k) {
        float vk = v[k];
        const float4* wrow = (const float4*)(w2s + k * 40);
        #pragma unroll
        for (int j = 0; j < 10; ++j) {
            float4 w = wrow[j];
            acc[j].x += vk * w.x; acc[j].y += vk * w.y;
            acc[j].z += vk * w.z; acc[j].w += vk * w.w;
        }
    }
    float d = dinv[i];
    float4* o = (float4*)(h2n + (size_t)i * 40);
    #pragma unroll
    for (int j = 0; j < 10; ++j)
        o[j] = make_float4(acc[j].x * d, acc[j].y * d, acc[j].z * d, acc[j].w * d);
}

// ---------------------------------------------------------------------------
// Aggregation layer 2 (F=40) + fused bias + log_softmax.  Wave per node,
// lanes 0..39 hold the feature row.
// ---------------------------------------------------------------------------
__global__ __launch_bounds__(256) void k_agg2(
        const float* __restrict__ h2n, const int* __restrict__ row_ptr,
        const int* __restrict__ csr_col, const float* __restrict__ dinv,
        const float* __restrict__ b2, float* __restrict__ out, int n) {
    int wid = threadIdx.x >> 6, lane = threadIdx.x & 63;
    int i = blockIdx.x * 4 + wid;
    if (i >= n) return;
    bool act = lane < 40;
    int start = row_ptr[i], end = row_ptr[i + 1];
    float acc = 0.f;
    int j = start;
    int c = (j < end) ? csr_col[j] : 0;
    while (j < end) {
        int jn = j + 1;
        int cn = (jn < end) ? csr_col[jn] : 0;   // prefetch next col
        if (act) acc += h2n[c * 40 + lane];
        c = cn; j = jn;
    }
    float d = dinv[i];
    float v = act ? (d * (acc + h2n[i * 40 + lane]) + b2[lane]) : -INFINITY;
    float m = v;
    #pragma unroll
    for (int o = 1; o < 64; o <<= 1) m = fmaxf(m, __shfl_xor(m, o));
    float ex = act ? __expf(v - m) : 0.f;
    float s = ex;
    #pragma unroll
    for (int o = 1; o < 64; o <<= 1) s += __shfl_xor(s, o);
    float ls = __logf(s) + m;
    if (act) out[i * 40 + lane] = v - ls;
}

extern "C" void kernel_launch(void* const* d_in, const int* in_sizes, int n_in,
                              void* d_out, int out_size, void* d_ws, size_t ws_size,
                              hipStream_t stream) {
    const float* x  = (const float*)d_in[0];
    const void*  ei = d_in[1];
    const float* W1 = (const float*)d_in[2];
    const float* b1 = (const float*)d_in[3];
    const float* W2 = (const float*)d_in[4];
    const float* b2 = (const float*)d_in[5];
    float* out = (float*)d_out;

    const int n = in_sizes[0] / 512;
    const int E = in_sizes[1] / 2;
    const int nch = (n + CHUNK - 1) / CHUNK;

    // workspace layout (256B aligned blocks)
    char* w = (char*)d_ws;
    size_t off = 0;
    auto take = [&](size_t bytes) { void* p = w + off; off = (off + bytes + 255) & ~(size_t)255; return p; };
    int*   flag    = (int*)take(4);
    float* dinv    = (float*)take((size_t)n * 4);
    int*   deg     = (int*)take((size_t)n * 4);
    int*   row_ptr = (int*)take((size_t)(n + 1) * 4);
    int*   cursor  = (int*)take((size_t)n * 4);
    int*   csum    = (int*)take(1024);
    int*   coff    = (int*)take(1024);
    float* hn      = (float*)take((size_t)n * 16 * 4);
    float* agg1    = (float*)take((size_t)n * 16 * 4);
    float* h2n     = (float*)take((size_t)n * 40 * 4);
    int*   csr_col = (int*)take((size_t)E * 4);
    (void)ws_size;

    const int nb  = (n + 255) / 256;
    const int eb  = (E + 255) / 256;
    const int nb4 = (n + 3) / 4;

    k_detect   <<<1, 64, 0, stream>>>((const int*)ei, flag);
    k_zero     <<<nb, 256, 0, stream>>>(deg, n);
    k_count    <<<eb, 256, 0, stream>>>(ei, flag, deg, E);
    k_dinv     <<<nb, 256, 0, stream>>>(deg, dinv, n);
    k_chunksum <<<nch, 256, 0, stream>>>(deg, csum, n);
    k_scanpart <<<1, 256, 0, stream>>>(csum, coff, nch, row_ptr, n, E);
    k_scanlocal<<<nch, 256, 0, stream>>>(deg, coff, row_ptr, cursor, n);
    k_scatter  <<<eb, 256, 0, stream>>>(ei, flag, cursor, csr_col, E);
    k_gemm1    <<<nb, 256, 0, stream>>>(x, W1, dinv, hn, n);
    k_agg1     <<<nb4, 256, 0, stream>>>(hn, row_ptr, csr_col, dinv, agg1, n);
    k_layer2   <<<nb, 256, 0, stream>>>(agg1, W2, b1, dinv, h2n, n);
    k_agg2     <<<nb4, 256, 0, stream>>>(h2n, row_ptr, csr_col, dinv, b2, out, n);
}

// Round 3
// 565.813 us; speedup vs baseline: 5.2007x; 1.4057x over previous
//
#include <hip/hip_runtime.h>
#include <math.h>

// ---------------------------------------------------------------------------
// GCN forward, CSR + 16-wide aggregation for BOTH layers.
// Key algebra #1: norm = dinv[r]*dinv[c] => pre-scale features by dinv[c],
//   post-scale row sums by dinv[r].
// Key algebra #2: W2 is linear and per-node => aggregate the 16-wide
//   u = relu(agg1+b1)*dinv and apply W2 AFTER aggregation (gather 64B/edge
//   instead of 160B/edge; table 6.4MB instead of 16MB).
// Pipeline:
//   1) detect edge_index dtype (int64 vs int32)
//   2) deg count (int atomics), dinv = rsqrt(1+deg)
//   3) row_ptr = exclusive scan(deg); scatter cols -> CSR
//   4) hn = (x @ W1) * dinv                      [thread-per-row, W1 in LDS]
//   5) k_agg1: t = dinv[i]*(hn[i]+sum hn[col]);  u[i] = relu(t+b1)*dinv[i]
//      [wave per node, 16 edge-slots x 4 lanes, float4 gathers]
//   6) k_agg2f: s = dinv[i]*(u[i]+sum u[col]);   out = log_softmax(s@W2+b2)
//      [same gather structure, GEMM+lsm fused in epilogue]
// ---------------------------------------------------------------------------

#define CHUNK 1024

__global__ void k_detect(const int* __restrict__ ei32, int* __restrict__ flag) {
    int t = threadIdx.x;
    bool z = (ei32[2 * t + 1] == 0);
    unsigned long long m = __ballot(z);
    if (t == 0) *flag = (m == 0xFFFFFFFFFFFFFFFFULL) ? 1 : 0;
}

__global__ void k_zero(int* __restrict__ p, int n) {
    int i = blockIdx.x * blockDim.x + threadIdx.x;
    if (i < n) p[i] = 0;
}

__global__ void k_count(const void* __restrict__ ei, const int* __restrict__ flag,
                        int* __restrict__ deg, int E) {
    int e = blockIdx.x * blockDim.x + threadIdx.x;
    if (e >= E) return;
    int r;
    if (*flag) r = (int)((const long long*)ei)[e];
    else       r = ((const int*)ei)[e];
    atomicAdd(&deg[r], 1);
}

__global__ void k_dinv(const int* __restrict__ deg, float* __restrict__ dinv, int n) {
    int i = blockIdx.x * blockDim.x + threadIdx.x;
    if (i < n) dinv[i] = rsqrtf(1.0f + (float)deg[i]);  // +1 = self-loop
}

// ---- 3-kernel exclusive scan of deg -> row_ptr (and cursor copy) ----
__global__ void k_chunksum(const int* __restrict__ deg, int* __restrict__ csum, int n) {
    __shared__ int ls[256];
    int tid = threadIdx.x;
    int base = blockIdx.x * CHUNK + tid * 4;
    int s = 0;
    #pragma unroll
    for (int t = 0; t < 4; ++t) { int idx = base + t; if (idx < n) s += deg[idx]; }
    ls[tid] = s; __syncthreads();
    for (int off = 128; off > 0; off >>= 1) {
        if (tid < off) ls[tid] += ls[tid + off];
        __syncthreads();
    }
    if (tid == 0) csum[blockIdx.x] = ls[0];
}

__global__ void k_scanpart(const int* __restrict__ csum, int* __restrict__ coff,
                           int nch, int* __restrict__ row_ptr, int n, int E) {
    __shared__ int ls[256];
    int tid = threadIdx.x;
    int v = (tid < nch) ? csum[tid] : 0;
    ls[tid] = v; __syncthreads();
    for (int off = 1; off < 256; off <<= 1) {
        int t = (tid >= off) ? ls[tid - off] : 0;
        __syncthreads();
        ls[tid] += t;
        __syncthreads();
    }
    coff[tid] = ls[tid] - v;  // exclusive
    if (tid == 0) row_ptr[n] = E;
}

__global__ void k_scanlocal(const int* __restrict__ deg, const int* __restrict__ coff,
                            int* __restrict__ row_ptr, int* __restrict__ cursor, int n) {
    __shared__ int ls[256];
    int tid = threadIdx.x, b = blockIdx.x;
    int base = b * CHUNK + tid * 4;
    int v[4]; int s = 0;
    #pragma unroll
    for (int t = 0; t < 4; ++t) {
        int idx = base + t;
        v[t] = (idx < n) ? deg[idx] : 0;
        s += v[t];
    }
    ls[tid] = s; __syncthreads();
    for (int off = 1; off < 256; off <<= 1) {
        int t = (tid >= off) ? ls[tid - off] : 0;
        __syncthreads();
        ls[tid] += t;
        __syncthreads();
    }
    int run = ls[tid] - s + coff[b];
    #pragma unroll
    for (int t = 0; t < 4; ++t) {
        int idx = base + t;
        if (idx < n) { row_ptr[idx] = run; cursor[idx] = run; }
        run += v[t];
    }
}

__global__ void k_scatter(const void* __restrict__ ei, const int* __restrict__ flag,
                          int* __restrict__ cursor, int* __restrict__ csr_col, int E) {
    int e = blockIdx.x * blockDim.x + threadIdx.x;
    if (e >= E) return;
    int r, c;
    if (*flag) { const long long* p = (const long long*)ei; r = (int)p[e]; c = (int)p[E + e]; }
    else       { const int* p = (const int*)ei;             r = p[e];      c = p[E + e]; }
    int pos = atomicAdd(&cursor[r], 1);
    csr_col[pos] = c;
}

// ---------------------------------------------------------------------------
// GEMM1: hn[row] = (x[row] @ W1) * dinv[row].  Thread per row; W1 (32KB) in
// LDS, all reads lane-uniform (broadcast, conflict-free).  Per wave-instr the
// 64 lanes touch 64 distinct 128B lines of x, each fully consumed over 8
// consecutive kq iterations (8KB working set, L1-resident).
// ---------------------------------------------------------------------------
__global__ __launch_bounds__(256) void k_gemm1(
        const float* __restrict__ x, const float* __restrict__ W1,
        const float* __restrict__ dinv, float* __restrict__ hn, int n) {
    __shared__ float w1s[512 * 16];
    int tid = threadIdx.x;
    for (int i = tid; i < 2048; i += 256)
        ((float4*)w1s)[i] = ((const float4*)W1)[i];
    __syncthreads();
    int row = blockIdx.x * 256 + tid;
    if (row >= n) return;

    float4 a0 = {0, 0, 0, 0}, a1 = {0, 0, 0, 0}, a2 = {0, 0, 0, 0}, a3 = {0, 0, 0, 0};
    const float4* xr = (const float4*)(x + (size_t)row * 512);
    #pragma unroll 4
    for (int kq = 0; kq < 128; ++kq) {
        float4 xv = xr[kq];
        const float4* w = (const float4*)(w1s + kq * 64);  // 4 k-rows of 16
        #pragma unroll
        for (int j = 0; j < 4; ++j) {
            float xk = (j == 0) ? xv.x : (j == 1) ? xv.y : (j == 2) ? xv.z : xv.w;
            float4 w0 = w[4 * j + 0], w1 = w[4 * j + 1], w2 = w[4 * j + 2], w3 = w[4 * j + 3];
            a0.x += xk * w0.x; a0.y += xk * w0.y; a0.z += xk * w0.z; a0.w += xk * w0.w;
            a1.x += xk * w1.x; a1.y += xk * w1.y; a1.z += xk * w1.z; a1.w += xk * w1.w;
            a2.x += xk * w2.x; a2.y += xk * w2.y; a2.z += xk * w2.z; a2.w += xk * w2.w;
            a3.x += xk * w3.x; a3.y += xk * w3.y; a3.z += xk * w3.z; a3.w += xk * w3.w;
        }
    }
    float d = dinv[row];
    float4* o = (float4*)(hn + (size_t)row * 16);
    o[0] = make_float4(a0.x * d, a0.y * d, a0.z * d, a0.w * d);
    o[1] = make_float4(a1.x * d, a1.y * d, a1.z * d, a1.w * d);
    o[2] = make_float4(a2.x * d, a2.y * d, a2.z * d, a2.w * d);
    o[3] = make_float4(a3.x * d, a3.y * d, a3.z * d, a3.w * d);
}

// ---------------------------------------------------------------------------
// Layer-1 aggregation + fused relu/b1/dinv: wave per node.
// Lane layout: slot = lane>>2 (16 edge slots), q = lane&3 (float4 within row).
// u[i] = relu(dinv[i]*(hn[i]+sum hn[col]) + b1) * dinv[i]
// ---------------------------------------------------------------------------
__global__ __launch_bounds__(256) void k_agg1(
        const float* __restrict__ hn, const int* __restrict__ row_ptr,
        const int* __restrict__ csr_col, const float* __restrict__ dinv,
        const float* __restrict__ b1, float* __restrict__ u, int n) {
    int wid = threadIdx.x >> 6, lane = threadIdx.x & 63;
    int i = blockIdx.x * 4 + wid;
    if (i >= n) return;
    int slot = lane >> 2, q = lane & 3;
    int start = row_ptr[i], end = row_ptr[i + 1];

    float4 acc = {0.f, 0.f, 0.f, 0.f};
    int j = start + slot;
    int c = (j < end) ? csr_col[j] : 0;
    while (j < end) {
        int jn = j + 16;
        int cn = (jn < end) ? csr_col[jn] : 0;   // prefetch next col
        float4 v = *(const float4*)(hn + (size_t)c * 16 + 4 * q);
        acc.x += v.x; acc.y += v.y; acc.z += v.z; acc.w += v.w;
        c = cn; j = jn;
    }
    #pragma unroll
    for (int off = 4; off < 64; off <<= 1) {
        acc.x += __shfl_xor(acc.x, off);
        acc.y += __shfl_xor(acc.y, off);
        acc.z += __shfl_xor(acc.z, off);
        acc.w += __shfl_xor(acc.w, off);
    }
    // every lane now holds the slot-sum for its q
    float d = dinv[i];
    float4 hs = *(const float4*)(hn + (size_t)i * 16 + 4 * q);
    float4 bb = *(const float4*)(b1 + 4 * q);
    float4 uo;
    uo.x = fmaxf((acc.x + hs.x) * d + bb.x, 0.f) * d;
    uo.y = fmaxf((acc.y + hs.y) * d + bb.y, 0.f) * d;
    uo.z = fmaxf((acc.z + hs.z) * d + bb.z, 0.f) * d;
    uo.w = fmaxf((acc.w + hs.w) * d + bb.w, 0.f) * d;
    if (lane < 4) *(float4*)(u + (size_t)i * 16 + 4 * q) = uo;  // 64B store
}

// ---------------------------------------------------------------------------
// Layer-2 aggregation (16-wide) + fused W2 GEMM + b2 + log_softmax.
// Wave per node; same gather structure; epilogue: shfl-broadcast the 16-wide
// aggregated s to all lanes, lane j (<40) computes out[j].
// ---------------------------------------------------------------------------
__global__ __launch_bounds__(256) void k_agg2f(
        const float* __restrict__ u, const int* __restrict__ row_ptr,
        const int* __restrict__ csr_col, const float* __restrict__ dinv,
        const float* __restrict__ W2, const float* __restrict__ b2,
        float* __restrict__ out, int n) {
    __shared__ float w2s[640];
    int tid = threadIdx.x;
    if (tid < 160) ((float4*)w2s)[tid] = ((const float4*)W2)[tid];
    __syncthreads();

    int wid = tid >> 6, lane = tid & 63;
    int i = blockIdx.x * 4 + wid;
    if (i >= n) return;
    int slot = lane >> 2, q = lane & 3;
    int start = row_ptr[i], end = row_ptr[i + 1];

    float4 acc = {0.f, 0.f, 0.f, 0.f};
    int j = start + slot;
    int c = (j < end) ? csr_col[j] : 0;
    while (j < end) {
        int jn = j + 16;
        int cn = (jn < end) ? csr_col[jn] : 0;
        float4 v = *(const float4*)(u + (size_t)c * 16 + 4 * q);
        acc.x += v.x; acc.y += v.y; acc.z += v.z; acc.w += v.w;
        c = cn; j = jn;
    }
    #pragma unroll
    for (int off = 4; off < 64; off <<= 1) {
        acc.x += __shfl_xor(acc.x, off);
        acc.y += __shfl_xor(acc.y, off);
        acc.z += __shfl_xor(acc.z, off);
        acc.w += __shfl_xor(acc.w, off);
    }
    float d = dinv[i];
    float4 us = *(const float4*)(u + (size_t)i * 16 + 4 * q);
    float4 s4;
    s4.x = (acc.x + us.x) * d;
    s4.y = (acc.y + us.y) * d;
    s4.z = (acc.z + us.z) * d;
    s4.w = (acc.w + us.w) * d;

    // GEMM 16x40: lane j accumulates out[j]; broadcast s from lanes 0..3
    bool act = lane < 40;
    float o = 0.f;
    #pragma unroll
    for (int q2 = 0; q2 < 4; ++q2) {
        float sx = __shfl(s4.x, q2);
        float sy = __shfl(s4.y, q2);
        float sz = __shfl(s4.z, q2);
        float sw = __shfl(s4.w, q2);
        if (act) {
            o += sx * w2s[(4 * q2 + 0) * 40 + lane];
            o += sy * w2s[(4 * q2 + 1) * 40 + lane];
            o += sz * w2s[(4 * q2 + 2) * 40 + lane];
            o += sw * w2s[(4 * q2 + 3) * 40 + lane];
        }
    }
    float v = act ? (o + b2[lane]) : -INFINITY;
    float m = v;
    #pragma unroll
    for (int off = 1; off < 64; off <<= 1) m = fmaxf(m, __shfl_xor(m, off));
    float ex = act ? __expf(v - m) : 0.f;
    float s = ex;
    #pragma unroll
    for (int off = 1; off < 64; off <<= 1) s += __shfl_xor(s, off);
    float ls = __logf(s) + m;
    if (act) out[(size_t)i * 40 + lane] = v - ls;
}

extern "C" void kernel_launch(void* const* d_in, const int* in_sizes, int n_in,
                              void* d_out, int out_size, void* d_ws, size_t ws_size,
                              hipStream_t stream) {
    const float* x  = (const float*)d_in[0];
    const void*  ei = d_in[1];
    const float* W1 = (const float*)d_in[2];
    const float* b1 = (const float*)d_in[3];
    const float* W2 = (const float*)d_in[4];
    const float* b2 = (const float*)d_in[5];
    float* out = (float*)d_out;

    const int n = in_sizes[0] / 512;
    const int E = in_sizes[1] / 2;
    const int nch = (n + CHUNK - 1) / CHUNK;

    // workspace layout (256B aligned blocks)
    char* w = (char*)d_ws;
    size_t off = 0;
    auto take = [&](size_t bytes) { void* p = w + off; off = (off + bytes + 255) & ~(size_t)255; return p; };
    int*   flag    = (int*)take(4);
    float* dinv    = (float*)take((size_t)n * 4);
    int*   deg     = (int*)take((size_t)n * 4);
    int*   row_ptr = (int*)take((size_t)(n + 1) * 4);
    int*   cursor  = (int*)take((size_t)n * 4);
    int*   csum    = (int*)take(1024);
    int*   coff    = (int*)take(1024);
    float* hn      = (float*)take((size_t)n * 16 * 4);
    float* u       = (float*)take((size_t)n * 16 * 4);
    int*   csr_col = (int*)take((size_t)E * 4);
    (void)ws_size;

    const int nb  = (n + 255) / 256;
    const int eb  = (E + 255) / 256;
    const int nb4 = (n + 3) / 4;

    k_detect   <<<1, 64, 0, stream>>>((const int*)ei, flag);
    k_zero     <<<nb, 256, 0, stream>>>(deg, n);
    k_count    <<<eb, 256, 0, stream>>>(ei, flag, deg, E);
    k_dinv     <<<nb, 256, 0, stream>>>(deg, dinv, n);
    k_chunksum <<<nch, 256, 0, stream>>>(deg, csum, n);
    k_scanpart <<<1, 256, 0, stream>>>(csum, coff, nch, row_ptr, n, E);
    k_scanlocal<<<nch, 256, 0, stream>>>(deg, coff, row_ptr, cursor, n);
    k_scatter  <<<eb, 256, 0, stream>>>(ei, flag, cursor, csr_col, E);
    k_gemm1    <<<nb, 256, 0, stream>>>(x, W1, dinv, hn, n);
    k_agg1     <<<nb4, 256, 0, stream>>>(hn, row_ptr, csr_col, dinv, b1, u, n);
    k_agg2f    <<<nb4, 256, 0, stream>>>(u, row_ptr, csr_col, dinv, W2, b2, out, n);
}

// Round 4
// 404.704 us; speedup vs baseline: 7.2710x; 1.3981x over previous
//
#include <hip/hip_runtime.h>
#include <math.h>

// ---------------------------------------------------------------------------
// GCN forward, CSR + 16-wide aggregation for BOTH layers.
// Algebra #1: norm = dinv[r]*dinv[c] => pre-scale features by dinv[c],
//   post-scale row sums by dinv[r].
// Algebra #2: W2 is linear => aggregate the 16-wide u = relu(.)*dinv and
//   apply W2 AFTER aggregation (64B/edge gather over a 6.4MB table).
// CSR build: two-level counting sort (k_bscatter -> k_bsort) instead of a
//   single random scatter; bounds every write to a small contiguous window
//   so L2 write-combines (R3: random 4B scatter caused 194MB HBM writeback).
// ---------------------------------------------------------------------------

#define CHUNK 1024
#define BSHIFT 7          // 128 rows per bucket
#define CHUNK_E 8192      // edges per k_bscatter block

__global__ void k_detect(const int* __restrict__ ei32, int* __restrict__ flag) {
    int t = threadIdx.x;
    bool z = (ei32[2 * t + 1] == 0);
    unsigned long long m = __ballot(z);
    if (t == 0) *flag = (m == 0xFFFFFFFFFFFFFFFFULL) ? 1 : 0;
}

__global__ void k_zero(int* __restrict__ p, int n) {
    int i = blockIdx.x * blockDim.x + threadIdx.x;
    if (i < n) p[i] = 0;
}

__global__ void k_count(const void* __restrict__ ei, const int* __restrict__ flag,
                        int* __restrict__ deg, int E) {
    int e = blockIdx.x * blockDim.x + threadIdx.x;
    if (e >= E) return;
    int r;
    if (*flag) r = (int)((const long long*)ei)[e];
    else       r = ((const int*)ei)[e];
    atomicAdd(&deg[r], 1);
}

__global__ void k_dinv(const int* __restrict__ deg, float* __restrict__ dinv, int n) {
    int i = blockIdx.x * blockDim.x + threadIdx.x;
    if (i < n) dinv[i] = rsqrtf(1.0f + (float)deg[i]);  // +1 = self-loop
}

// ---- 3-kernel exclusive scan of deg -> row_ptr ----
__global__ void k_chunksum(const int* __restrict__ deg, int* __restrict__ csum, int n) {
    __shared__ int ls[256];
    int tid = threadIdx.x;
    int base = blockIdx.x * CHUNK + tid * 4;
    int s = 0;
    #pragma unroll
    for (int t = 0; t < 4; ++t) { int idx = base + t; if (idx < n) s += deg[idx]; }
    ls[tid] = s; __syncthreads();
    for (int off = 128; off > 0; off >>= 1) {
        if (tid < off) ls[tid] += ls[tid + off];
        __syncthreads();
    }
    if (tid == 0) csum[blockIdx.x] = ls[0];
}

__global__ void k_scanpart(const int* __restrict__ csum, int* __restrict__ coff,
                           int nch, int* __restrict__ row_ptr, int n, int E) {
    __shared__ int ls[256];
    int tid = threadIdx.x;
    int v = (tid < nch) ? csum[tid] : 0;
    ls[tid] = v; __syncthreads();
    for (int off = 1; off < 256; off <<= 1) {
        int t = (tid >= off) ? ls[tid - off] : 0;
        __syncthreads();
        ls[tid] += t;
        __syncthreads();
    }
    coff[tid] = ls[tid] - v;  // exclusive
    if (tid == 0) row_ptr[n] = E;
}

__global__ void k_scanlocal(const int* __restrict__ deg, const int* __restrict__ coff,
                            int* __restrict__ row_ptr, int n) {
    __shared__ int ls[256];
    int tid = threadIdx.x, b = blockIdx.x;
    int base = b * CHUNK + tid * 4;
    int v[4]; int s = 0;
    #pragma unroll
    for (int t = 0; t < 4; ++t) {
        int idx = base + t;
        v[t] = (idx < n) ? deg[idx] : 0;
        s += v[t];
    }
    ls[tid] = s; __syncthreads();
    for (int off = 1; off < 256; off <<= 1) {
        int t = (tid >= off) ? ls[tid - off] : 0;
        __syncthreads();
        ls[tid] += t;
        __syncthreads();
    }
    int run = ls[tid] - s + coff[b];
    #pragma unroll
    for (int t = 0; t < 4; ++t) {
        int idx = base + t;
        if (idx < n) row_ptr[idx] = run;
        run += v[t];
    }
}

__global__ void k_initcur(const int* __restrict__ row_ptr, int* __restrict__ bcur,
                          int n, int nbuck) {
    int i = blockIdx.x * blockDim.x + threadIdx.x;
    if (i < nbuck) bcur[i] = row_ptr[min(n, i << BSHIFT)];
}

// ---------------------------------------------------------------------------
// Counting-sort pass B: bucket edges (by row>>7) into contiguous per-bucket
// segments of pair_buf. Per (block,bucket) writes form one contiguous run.
// ---------------------------------------------------------------------------
__global__ __launch_bounds__(256) void k_bscatter(
        const void* __restrict__ ei, const int* __restrict__ flag,
        int* __restrict__ bcur, int2* __restrict__ pair, int E, int nbuck) {
    __shared__ int cnt[1024];
    __shared__ int runs[1024];
    int tid = threadIdx.x;
    for (int i = tid; i < nbuck; i += 256) cnt[i] = 0;
    __syncthreads();
    int e0 = blockIdx.x * CHUNK_E;
    int e1 = min(E, e0 + CHUNK_E);
    bool f = (*flag) != 0;
    for (int e = e0 + tid; e < e1; e += 256) {
        int r = f ? (int)((const long long*)ei)[e] : ((const int*)ei)[e];
        atomicAdd(&cnt[r >> BSHIFT], 1);
    }
    __syncthreads();
    for (int i = tid; i < nbuck; i += 256) {
        int c = cnt[i];
        runs[i] = (c > 0) ? atomicAdd(&bcur[i], c) : 0;
        cnt[i] = 0;  // reuse as local cursor
    }
    __syncthreads();
    for (int e = e0 + tid; e < e1; e += 256) {
        int r, c;
        if (f) { const long long* p = (const long long*)ei; r = (int)p[e]; c = (int)p[E + e]; }
        else   { const int* p = (const int*)ei;             r = p[e];      c = p[E + e]; }
        int b = r >> BSHIFT;
        int pos = runs[b] + atomicAdd(&cnt[b], 1);
        pair[pos] = make_int2(r, c);
    }
}

// ---------------------------------------------------------------------------
// Counting-sort pass C: one block per bucket; scatter cols to final CSR
// positions via LDS per-row cursors. Writes confined to the bucket's ~16KB
// csr_col window (L2 write-combines).
// ---------------------------------------------------------------------------
__global__ __launch_bounds__(256) void k_bsort(
        const int2* __restrict__ pair, const int* __restrict__ row_ptr,
        int* __restrict__ csr_col, int n) {
    __shared__ int cur[128];
    int b = blockIdx.x;
    int lo = b << BSHIFT, hi = min(n, lo + 128);
    int tid = threadIdx.x;
    if (tid < hi - lo) cur[tid] = row_ptr[lo + tid];
    __syncthreads();
    int s = row_ptr[lo], e = row_ptr[hi];
    for (int j = s + tid; j < e; j += 256) {
        int2 p = pair[j];
        int pos = atomicAdd(&cur[p.x - lo], 1);
        csr_col[pos] = p.y;
    }
}

// ---------------------------------------------------------------------------
// GEMM1: hn[row] = (x[row] @ W1) * dinv[row].  Thread per row; W1 (32KB) in
// LDS, all reads lane-uniform (broadcast, conflict-free).
// ---------------------------------------------------------------------------
__global__ __launch_bounds__(256) void k_gemm1(
        const float* __restrict__ x, const float* __restrict__ W1,
        const float* __restrict__ dinv, float* __restrict__ hn, int n) {
    __shared__ float w1s[512 * 16];
    int tid = threadIdx.x;
    for (int i = tid; i < 2048; i += 256)
        ((float4*)w1s)[i] = ((const float4*)W1)[i];
    __syncthreads();
    int row = blockIdx.x * 256 + tid;
    if (row >= n) return;

    float4 a0 = {0, 0, 0, 0}, a1 = {0, 0, 0, 0}, a2 = {0, 0, 0, 0}, a3 = {0, 0, 0, 0};
    const float4* xr = (const float4*)(x + (size_t)row * 512);
    #pragma unroll 4
    for (int kq = 0; kq < 128; ++kq) {
        float4 xv = xr[kq];
        const float4* w = (const float4*)(w1s + kq * 64);  // 4 k-rows of 16
        #pragma unroll
        for (int j = 0; j < 4; ++j) {
            float xk = (j == 0) ? xv.x : (j == 1) ? xv.y : (j == 2) ? xv.z : xv.w;
            float4 w0 = w[4 * j + 0], w1 = w[4 * j + 1], w2 = w[4 * j + 2], w3 = w[4 * j + 3];
            a0.x += xk * w0.x; a0.y += xk * w0.y; a0.z += xk * w0.z; a0.w += xk * w0.w;
            a1.x += xk * w1.x; a1.y += xk * w1.y; a1.z += xk * w1.z; a1.w += xk * w1.w;
            a2.x += xk * w2.x; a2.y += xk * w2.y; a2.z += xk * w2.z; a2.w += xk * w2.w;
            a3.x += xk * w3.x; a3.y += xk * w3.y; a3.z += xk * w3.z; a3.w += xk * w3.w;
        }
    }
    float d = dinv[row];
    float4* o = (float4*)(hn + (size_t)row * 16);
    o[0] = make_float4(a0.x * d, a0.y * d, a0.z * d, a0.w * d);
    o[1] = make_float4(a1.x * d, a1.y * d, a1.z * d, a1.w * d);
    o[2] = make_float4(a2.x * d, a2.y * d, a2.z * d, a2.w * d);
    o[3] = make_float4(a3.x * d, a3.y * d, a3.z * d, a3.w * d);
}

// ---------------------------------------------------------------------------
// Layer-1 aggregation + fused relu/b1/dinv: wave per node.
// Lane layout: slot = lane>>2 (16 edge slots), q = lane&3 (float4 of row).
// u[i] = relu(dinv[i]*(hn[i]+sum hn[col]) + b1) * dinv[i]
// ---------------------------------------------------------------------------
__global__ __launch_bounds__(256) void k_agg1(
        const float* __restrict__ hn, const int* __restrict__ row_ptr,
        const int* __restrict__ csr_col, const float* __restrict__ dinv,
        const float* __restrict__ b1, float* __restrict__ u, int n) {
    int wid = threadIdx.x >> 6, lane = threadIdx.x & 63;
    int i = blockIdx.x * 4 + wid;
    if (i >= n) return;
    int slot = lane >> 2, q = lane & 3;
    int start = row_ptr[i], end = row_ptr[i + 1];

    float4 acc = {0.f, 0.f, 0.f, 0.f};
    int j = start + slot;
    int c = (j < end) ? csr_col[j] : 0;
    while (j < end) {
        int jn = j + 16;
        int cn = (jn < end) ? csr_col[jn] : 0;   // prefetch next col
        float4 v = *(const float4*)(hn + (size_t)c * 16 + 4 * q);
        acc.x += v.x; acc.y += v.y; acc.z += v.z; acc.w += v.w;
        c = cn; j = jn;
    }
    #pragma unroll
    for (int off = 4; off < 64; off <<= 1) {
        acc.x += __shfl_xor(acc.x, off);
        acc.y += __shfl_xor(acc.y, off);
        acc.z += __shfl_xor(acc.z, off);
        acc.w += __shfl_xor(acc.w, off);
    }
    float d = dinv[i];
    float4 hs = *(const float4*)(hn + (size_t)i * 16 + 4 * q);
    float4 bb = *(const float4*)(b1 + 4 * q);
    float4 uo;
    uo.x = fmaxf((acc.x + hs.x) * d + bb.x, 0.f) * d;
    uo.y = fmaxf((acc.y + hs.y) * d + bb.y, 0.f) * d;
    uo.z = fmaxf((acc.z + hs.z) * d + bb.z, 0.f) * d;
    uo.w = fmaxf((acc.w + hs.w) * d + bb.w, 0.f) * d;
    if (lane < 4) *(float4*)(u + (size_t)i * 16 + 4 * q) = uo;  // 64B store
}

// ---------------------------------------------------------------------------
// Layer-2 aggregation (16-wide) + fused W2 GEMM + b2 + log_softmax.
// ---------------------------------------------------------------------------
__global__ __launch_bounds__(256) void k_agg2f(
        const float* __restrict__ u, const int* __restrict__ row_ptr,
        const int* __restrict__ csr_col, const float* __restrict__ dinv,
        const float* __restrict__ W2, const float* __restrict__ b2,
        float* __restrict__ out, int n) {
    __shared__ float w2s[640];
    int tid = threadIdx.x;
    if (tid < 160) ((float4*)w2s)[tid] = ((const float4*)W2)[tid];
    __syncthreads();

    int wid = tid >> 6, lane = tid & 63;
    int i = blockIdx.x * 4 + wid;
    if (i >= n) return;
    int slot = lane >> 2, q = lane & 3;
    int start = row_ptr[i], end = row_ptr[i + 1];

    float4 acc = {0.f, 0.f, 0.f, 0.f};
    int j = start + slot;
    int c = (j < end) ? csr_col[j] : 0;
    while (j < end) {
        int jn = j + 16;
        int cn = (jn < end) ? csr_col[jn] : 0;
        float4 v = *(const float4*)(u + (size_t)c * 16 + 4 * q);
        acc.x += v.x; acc.y += v.y; acc.z += v.z; acc.w += v.w;
        c = cn; j = jn;
    }
    #pragma unroll
    for (int off = 4; off < 64; off <<= 1) {
        acc.x += __shfl_xor(acc.x, off);
        acc.y += __shfl_xor(acc.y, off);
        acc.z += __shfl_xor(acc.z, off);
        acc.w += __shfl_xor(acc.w, off);
    }
    float d = dinv[i];
    float4 us = *(const float4*)(u + (size_t)i * 16 + 4 * q);
    float4 s4;
    s4.x = (acc.x + us.x) * d;
    s4.y = (acc.y + us.y) * d;
    s4.z = (acc.z + us.z) * d;
    s4.w = (acc.w + us.w) * d;

    // GEMM 16x40: lane j (<40) accumulates out[j]; broadcast s from lanes 0..3
    bool act = lane < 40;
    float o = 0.f;
    #pragma unroll
    for (int q2 = 0; q2 < 4; ++q2) {
        float sx = __shfl(s4.x, q2);
        float sy = __shfl(s4.y, q2);
        float sz = __shfl(s4.z, q2);
        float sw = __shfl(s4.w, q2);
        if (act) {
            o += sx * w2s[(4 * q2 + 0) * 40 + lane];
            o += sy * w2s[(4 * q2 + 1) * 40 + lane];
            o += sz * w2s[(4 * q2 + 2) * 40 + lane];
            o += sw * w2s[(4 * q2 + 3) * 40 + lane];
        }
    }
    float v = act ? (o + b2[lane]) : -INFINITY;
    float m = v;
    #pragma unroll
    for (int off = 1; off < 64; off <<= 1) m = fmaxf(m, __shfl_xor(m, off));
    float ex = act ? __expf(v - m) : 0.f;
    float s = ex;
    #pragma unroll
    for (int off = 1; off < 64; off <<= 1) s += __shfl_xor(s, off);
    float ls = __logf(s) + m;
    if (act) out[(size_t)i * 40 + lane] = v - ls;
}

extern "C" void kernel_launch(void* const* d_in, const int* in_sizes, int n_in,
                              void* d_out, int out_size, void* d_ws, size_t ws_size,
                              hipStream_t stream) {
    const float* x  = (const float*)d_in[0];
    const void*  ei = d_in[1];
    const float* W1 = (const float*)d_in[2];
    const float* b1 = (const float*)d_in[3];
    const float* W2 = (const float*)d_in[4];
    const float* b2 = (const float*)d_in[5];
    float* out = (float*)d_out;

    const int n = in_sizes[0] / 512;
    const int E = in_sizes[1] / 2;
    const int nch = (n + CHUNK - 1) / CHUNK;
    const int nbuck = (n + 127) >> BSHIFT;   // 128 rows per bucket (<=1024 buckets)

    // workspace layout (256B aligned blocks)
    char* w = (char*)d_ws;
    size_t off = 0;
    auto take = [&](size_t bytes) { void* p = w + off; off = (off + bytes + 255) & ~(size_t)255; return p; };
    int*   flag    = (int*)take(4);
    float* dinv    = (float*)take((size_t)n * 4);
    int*   deg     = (int*)take((size_t)n * 4);
    int*   row_ptr = (int*)take((size_t)(n + 1) * 4);
    int*   bcur    = (int*)take(4096);
    int*   csum    = (int*)take(1024);
    int*   coff    = (int*)take(1024);
    float* hn      = (float*)take((size_t)n * 16 * 4);
    float* u       = (float*)take((size_t)n * 16 * 4);
    int*   csr_col = (int*)take((size_t)E * 4);
    int2*  pair    = (int2*)take((size_t)E * 8);
    (void)ws_size;

    const int nb  = (n + 255) / 256;
    const int eb  = (E + 255) / 256;
    const int nb4 = (n + 3) / 4;
    const int nbB = (E + CHUNK_E - 1) / CHUNK_E;

    k_detect   <<<1, 64, 0, stream>>>((const int*)ei, flag);
    k_zero     <<<nb, 256, 0, stream>>>(deg, n);
    k_count    <<<eb, 256, 0, stream>>>(ei, flag, deg, E);
    k_dinv     <<<nb, 256, 0, stream>>>(deg, dinv, n);
    k_chunksum <<<nch, 256, 0, stream>>>(deg, csum, n);
    k_scanpart <<<1, 256, 0, stream>>>(csum, coff, nch, row_ptr, n, E);
    k_scanlocal<<<nch, 256, 0, stream>>>(deg, coff, row_ptr, n);
    k_initcur  <<<(nbuck + 255) / 256, 256, 0, stream>>>(row_ptr, bcur, n, nbuck);
    k_bscatter <<<nbB, 256, 0, stream>>>(ei, flag, bcur, pair, E, nbuck);
    k_bsort    <<<nbuck, 256, 0, stream>>>(pair, row_ptr, csr_col, n);
    k_gemm1    <<<nb, 256, 0, stream>>>(x, W1, dinv, hn, n);
    k_agg1     <<<nb4, 256, 0, stream>>>(hn, row_ptr, csr_col, dinv, b1, u, n);
    k_agg2f    <<<nb4, 256, 0, stream>>>(u, row_ptr, csr_col, dinv, W2, b2, out, n);
}

// Round 5
// 283.419 us; speedup vs baseline: 10.3825x; 1.4279x over previous
//
#include <hip/hip_runtime.h>
#include <math.h>

// ---------------------------------------------------------------------------
// GCN forward, CSR + 16-wide aggregation for BOTH layers.
// Algebra #1: norm = dinv[r]*dinv[c] => pre-scale features by dinv[c],
//   post-scale row sums by dinv[r].
// Algebra #2: W2 is linear => aggregate the 16-wide u = relu(.)*dinv and
//   apply W2 AFTER aggregation (64B/edge gather over a 6.4MB table).
// CSR build (all hierarchical, no large random atomic/scatter target):
//   k_bhist:   LDS histogram over 782 row-buckets -> bcnt  (R4: k_count's
//              3.2M random global atomics caused 100MB HBM writeback)
//   k_bscan:   single-block scan -> bbase/bcur
//   k_bscatter:bucket (r,c) pairs into contiguous per-bucket segments
//   k_bsort2:  per bucket: LDS 128-row histogram -> local scan -> row_ptr,
//              dinv (fused rsqrt), then LDS-cursor scatter -> csr_col
// ---------------------------------------------------------------------------

#define BSHIFT 7          // 128 rows per bucket
#define CHUNK_E 8192      // edges per bucketing block

__global__ void k_detect(const int* __restrict__ ei32, int* __restrict__ flag) {
    int t = threadIdx.x;
    bool z = (ei32[2 * t + 1] == 0);
    unsigned long long m = __ballot(z);
    if (t == 0) *flag = (m == 0xFFFFFFFFFFFFFFFFULL) ? 1 : 0;
}

__global__ void k_zero(int* __restrict__ p, int n) {
    int i = blockIdx.x * blockDim.x + threadIdx.x;
    if (i < n) p[i] = 0;
}

// ---------------------------------------------------------------------------
// Pass A: per-block LDS histogram of row-buckets; <=nbuck global atomics/block.
// ---------------------------------------------------------------------------
__global__ __launch_bounds__(256) void k_bhist(
        const void* __restrict__ ei, const int* __restrict__ flag,
        int* __restrict__ bcnt, int E, int nbuck) {
    __shared__ int cnt[1024];
    int tid = threadIdx.x;
    for (int i = tid; i < nbuck; i += 256) cnt[i] = 0;
    __syncthreads();
    int e0 = blockIdx.x * CHUNK_E;
    int e1 = min(E, e0 + CHUNK_E);
    bool f = (*flag) != 0;
    for (int e = e0 + tid; e < e1; e += 256) {
        int r = f ? (int)((const long long*)ei)[e] : ((const int*)ei)[e];
        atomicAdd(&cnt[r >> BSHIFT], 1);
    }
    __syncthreads();
    for (int i = tid; i < nbuck; i += 256)
        if (cnt[i]) atomicAdd(&bcnt[i], cnt[i]);
}

// ---------------------------------------------------------------------------
// Scan bucket counts -> bbase (exclusive), bcur (working copy).
// ---------------------------------------------------------------------------
__global__ __launch_bounds__(1024) void k_bscan(
        const int* __restrict__ bcnt, int* __restrict__ bbase,
        int* __restrict__ bcur, int nbuck, int E,
        int* __restrict__ row_ptr, int n) {
    __shared__ int ls[1024];
    int t = threadIdx.x;
    int v = (t < nbuck) ? bcnt[t] : 0;
    ls[t] = v; __syncthreads();
    for (int off = 1; off < 1024; off <<= 1) {
        int tmp = (t >= off) ? ls[t - off] : 0;
        __syncthreads();
        ls[t] += tmp;
        __syncthreads();
    }
    int ex = ls[t] - v;  // exclusive
    if (t < nbuck) { bbase[t] = ex; bcur[t] = ex; }
    if (t == 0) { bbase[nbuck] = E; row_ptr[n] = E; }
}

// ---------------------------------------------------------------------------
// Pass B: bucket edges into contiguous per-bucket segments of pair buffer.
// ---------------------------------------------------------------------------
__global__ __launch_bounds__(256) void k_bscatter(
        const void* __restrict__ ei, const int* __restrict__ flag,
        int* __restrict__ bcur, int2* __restrict__ pair, int E, int nbuck) {
    __shared__ int cnt[1024];
    __shared__ int runs[1024];
    int tid = threadIdx.x;
    for (int i = tid; i < nbuck; i += 256) cnt[i] = 0;
    __syncthreads();
    int e0 = blockIdx.x * CHUNK_E;
    int e1 = min(E, e0 + CHUNK_E);
    bool f = (*flag) != 0;
    for (int e = e0 + tid; e < e1; e += 256) {
        int r = f ? (int)((const long long*)ei)[e] : ((const int*)ei)[e];
        atomicAdd(&cnt[r >> BSHIFT], 1);
    }
    __syncthreads();
    for (int i = tid; i < nbuck; i += 256) {
        int c = cnt[i];
        runs[i] = (c > 0) ? atomicAdd(&bcur[i], c) : 0;
        cnt[i] = 0;  // reuse as local cursor
    }
    __syncthreads();
    for (int e = e0 + tid; e < e1; e += 256) {
        int r, c;
        if (f) { const long long* p = (const long long*)ei; r = (int)p[e]; c = (int)p[E + e]; }
        else   { const int* p = (const int*)ei;             r = p[e];      c = p[E + e]; }
        int b = r >> BSHIFT;
        int pos = runs[b] + atomicAdd(&cnt[b], 1);
        pair[pos] = make_int2(r, c);
    }
}

// ---------------------------------------------------------------------------
// Pass C: one block per bucket. LDS histogram -> local exclusive scan ->
// row_ptr + dinv (fused), then LDS-cursor scatter to csr_col (writes confined
// to the bucket's ~16KB window; L2 write-combines).
// ---------------------------------------------------------------------------
__global__ __launch_bounds__(256) void k_bsort2(
        const int2* __restrict__ pair, const int* __restrict__ bbase,
        int* __restrict__ row_ptr, float* __restrict__ dinv,
        int* __restrict__ csr_col, int n) {
    __shared__ int cnt[128];
    __shared__ int scn[128];
    __shared__ int cur[128];
    int b = blockIdx.x;
    int lo = b << BSHIFT, hi = min(n, lo + 128);
    int nr = hi - lo;
    int tid = threadIdx.x;
    if (tid < 128) cnt[tid] = 0;
    __syncthreads();
    int s = bbase[b], e = bbase[b + 1];
    for (int j = s + tid; j < e; j += 256)
        atomicAdd(&cnt[pair[j].x - lo], 1);
    __syncthreads();
    if (tid < 128) scn[tid] = cnt[tid];
    __syncthreads();
    for (int off = 1; off < 128; off <<= 1) {
        int tval = (tid < 128 && tid >= off) ? scn[tid - off] : 0;
        __syncthreads();
        if (tid < 128) scn[tid] += tval;
        __syncthreads();
    }
    if (tid < 128) {
        int rp = s + scn[tid] - cnt[tid];  // exclusive
        cur[tid] = rp;
        if (tid < nr) {
            row_ptr[lo + tid] = rp;
            dinv[lo + tid] = rsqrtf(1.0f + (float)cnt[tid]);  // +1 self-loop
        }
    }
    __syncthreads();
    for (int j = s + tid; j < e; j += 256) {
        int2 p = pair[j];
        int pos = atomicAdd(&cur[p.x - lo], 1);
        csr_col[pos] = p.y;
    }
}

// ---------------------------------------------------------------------------
// GEMM1: hn[row] = (x[row] @ W1) * dinv[row].  Thread per row; W1 (32KB) in
// LDS, all reads lane-uniform (broadcast, conflict-free).
// ---------------------------------------------------------------------------
__global__ __launch_bounds__(256) void k_gemm1(
        const float* __restrict__ x, const float* __restrict__ W1,
        const float* __restrict__ dinv, float* __restrict__ hn, int n) {
    __shared__ float w1s[512 * 16];
    int tid = threadIdx.x;
    for (int i = tid; i < 2048; i += 256)
        ((float4*)w1s)[i] = ((const float4*)W1)[i];
    __syncthreads();
    int row = blockIdx.x * 256 + tid;
    if (row >= n) return;

    float4 a0 = {0, 0, 0, 0}, a1 = {0, 0, 0, 0}, a2 = {0, 0, 0, 0}, a3 = {0, 0, 0, 0};
    const float4* xr = (const float4*)(x + (size_t)row * 512);
    #pragma unroll 4
    for (int kq = 0; kq < 128; ++kq) {
        float4 xv = xr[kq];
        const float4* w = (const float4*)(w1s + kq * 64);  // 4 k-rows of 16
        #pragma unroll
        for (int j = 0; j < 4; ++j) {
            float xk = (j == 0) ? xv.x : (j == 1) ? xv.y : (j == 2) ? xv.z : xv.w;
            float4 w0 = w[4 * j + 0], w1 = w[4 * j + 1], w2 = w[4 * j + 2], w3 = w[4 * j + 3];
            a0.x += xk * w0.x; a0.y += xk * w0.y; a0.z += xk * w0.z; a0.w += xk * w0.w;
            a1.x += xk * w1.x; a1.y += xk * w1.y; a1.z += xk * w1.z; a1.w += xk * w1.w;
            a2.x += xk * w2.x; a2.y += xk * w2.y; a2.z += xk * w2.z; a2.w += xk * w2.w;
            a3.x += xk * w3.x; a3.y += xk * w3.y; a3.z += xk * w3.z; a3.w += xk * w3.w;
        }
    }
    float d = dinv[row];
    float4* o = (float4*)(hn + (size_t)row * 16);
    o[0] = make_float4(a0.x * d, a0.y * d, a0.z * d, a0.w * d);
    o[1] = make_float4(a1.x * d, a1.y * d, a1.z * d, a1.w * d);
    o[2] = make_float4(a2.x * d, a2.y * d, a2.z * d, a2.w * d);
    o[3] = make_float4(a3.x * d, a3.y * d, a3.z * d, a3.w * d);
}

// ---------------------------------------------------------------------------
// Layer-1 aggregation + fused relu/b1/dinv: wave per node.
// Lane layout: slot = lane>>2 (16 edge slots), q = lane&3 (float4 of row).
// u[i] = relu(dinv[i]*(hn[i]+sum hn[col]) + b1) * dinv[i]
// ---------------------------------------------------------------------------
__global__ __launch_bounds__(256) void k_agg1(
        const float* __restrict__ hn, const int* __restrict__ row_ptr,
        const int* __restrict__ csr_col, const float* __restrict__ dinv,
        const float* __restrict__ b1, float* __restrict__ u, int n) {
    int wid = threadIdx.x >> 6, lane = threadIdx.x & 63;
    int i = blockIdx.x * 4 + wid;
    if (i >= n) return;
    int slot = lane >> 2, q = lane & 3;
    int start = row_ptr[i], end = row_ptr[i + 1];

    float4 acc = {0.f, 0.f, 0.f, 0.f};
    int j = start + slot;
    int c = (j < end) ? csr_col[j] : 0;
    while (j < end) {
        int jn = j + 16;
        int cn = (jn < end) ? csr_col[jn] : 0;   // prefetch next col
        float4 v = *(const float4*)(hn + (size_t)c * 16 + 4 * q);
        acc.x += v.x; acc.y += v.y; acc.z += v.z; acc.w += v.w;
        c = cn; j = jn;
    }
    #pragma unroll
    for (int off = 4; off < 64; off <<= 1) {
        acc.x += __shfl_xor(acc.x, off);
        acc.y += __shfl_xor(acc.y, off);
        acc.z += __shfl_xor(acc.z, off);
        acc.w += __shfl_xor(acc.w, off);
    }
    float d = dinv[i];
    float4 hs = *(const float4*)(hn + (size_t)i * 16 + 4 * q);
    float4 bb = *(const float4*)(b1 + 4 * q);
    float4 uo;
    uo.x = fmaxf((acc.x + hs.x) * d + bb.x, 0.f) * d;
    uo.y = fmaxf((acc.y + hs.y) * d + bb.y, 0.f) * d;
    uo.z = fmaxf((acc.z + hs.z) * d + bb.z, 0.f) * d;
    uo.w = fmaxf((acc.w + hs.w) * d + bb.w, 0.f) * d;
    if (lane < 4) *(float4*)(u + (size_t)i * 16 + 4 * q) = uo;  // 64B store
}

// ---------------------------------------------------------------------------
// Layer-2 aggregation (16-wide) + fused W2 GEMM + b2 + log_softmax.
// ---------------------------------------------------------------------------
__global__ __launch_bounds__(256) void k_agg2f(
        const float* __restrict__ u, const int* __restrict__ row_ptr,
        const int* __restrict__ csr_col, const float* __restrict__ dinv,
        const float* __restrict__ W2, const float* __restrict__ b2,
        float* __restrict__ out, int n) {
    __shared__ float w2s[640];
    int tid = threadIdx.x;
    if (tid < 160) ((float4*)w2s)[tid] = ((const float4*)W2)[tid];
    __syncthreads();

    int wid = tid >> 6, lane = tid & 63;
    int i = blockIdx.x * 4 + wid;
    if (i >= n) return;
    int slot = lane >> 2, q = lane & 3;
    int start = row_ptr[i], end = row_ptr[i + 1];

    float4 acc = {0.f, 0.f, 0.f, 0.f};
    int j = start + slot;
    int c = (j < end) ? csr_col[j] : 0;
    while (j < end) {
        int jn = j + 16;
        int cn = (jn < end) ? csr_col[jn] : 0;
        float4 v = *(const float4*)(u + (size_t)c * 16 + 4 * q);
        acc.x += v.x; acc.y += v.y; acc.z += v.z; acc.w += v.w;
        c = cn; j = jn;
    }
    #pragma unroll
    for (int off = 4; off < 64; off <<= 1) {
        acc.x += __shfl_xor(acc.x, off);
        acc.y += __shfl_xor(acc.y, off);
        acc.z += __shfl_xor(acc.z, off);
        acc.w += __shfl_xor(acc.w, off);
    }
    float d = dinv[i];
    float4 us = *(const float4*)(u + (size_t)i * 16 + 4 * q);
    float4 s4;
    s4.x = (acc.x + us.x) * d;
    s4.y = (acc.y + us.y) * d;
    s4.z = (acc.z + us.z) * d;
    s4.w = (acc.w + us.w) * d;

    // GEMM 16x40: lane j (<40) accumulates out[j]; broadcast s from lanes 0..3
    bool act = lane < 40;
    float o = 0.f;
    #pragma unroll
    for (int q2 = 0; q2 < 4; ++q2) {
        float sx = __shfl(s4.x, q2);
        float sy = __shfl(s4.y, q2);
        float sz = __shfl(s4.z, q2);
        float sw = __shfl(s4.w, q2);
        if (act) {
            o += sx * w2s[(4 * q2 + 0) * 40 + lane];
            o += sy * w2s[(4 * q2 + 1) * 40 + lane];
            o += sz * w2s[(4 * q2 + 2) * 40 + lane];
            o += sw * w2s[(4 * q2 + 3) * 40 + lane];
        }
    }
    float v = act ? (o + b2[lane]) : -INFINITY;
    float m = v;
    #pragma unroll
    for (int off = 1; off < 64; off <<= 1) m = fmaxf(m, __shfl_xor(m, off));
    float ex = act ? __expf(v - m) : 0.f;
    float s = ex;
    #pragma unroll
    for (int off = 1; off < 64; off <<= 1) s += __shfl_xor(s, off);
    float ls = __logf(s) + m;
    if (act) out[(size_t)i * 40 + lane] = v - ls;
}

extern "C" void kernel_launch(void* const* d_in, const int* in_sizes, int n_in,
                              void* d_out, int out_size, void* d_ws, size_t ws_size,
                              hipStream_t stream) {
    const float* x  = (const float*)d_in[0];
    const void*  ei = d_in[1];
    const float* W1 = (const float*)d_in[2];
    const float* b1 = (const float*)d_in[3];
    const float* W2 = (const float*)d_in[4];
    const float* b2 = (const float*)d_in[5];
    float* out = (float*)d_out;

    const int n = in_sizes[0] / 512;
    const int E = in_sizes[1] / 2;
    const int nbuck = (n + 127) >> BSHIFT;   // 128 rows/bucket (<=1024 buckets)

    // workspace layout (256B aligned blocks)
    char* w = (char*)d_ws;
    size_t off = 0;
    auto take = [&](size_t bytes) { void* p = w + off; off = (off + bytes + 255) & ~(size_t)255; return p; };
    int*   flag    = (int*)take(4);
    float* dinv    = (float*)take((size_t)n * 4);
    int*   row_ptr = (int*)take((size_t)(n + 1) * 4);
    int*   bcnt    = (int*)take(4096);
    int*   bbase   = (int*)take(4100);
    int*   bcur    = (int*)take(4096);
    float* hn      = (float*)take((size_t)n * 16 * 4);
    float* u       = (float*)take((size_t)n * 16 * 4);
    int*   csr_col = (int*)take((size_t)E * 4);
    int2*  pair    = (int2*)take((size_t)E * 8);
    (void)ws_size;

    const int nb  = (n + 255) / 256;
    const int nb4 = (n + 3) / 4;
    const int nbB = (E + CHUNK_E - 1) / CHUNK_E;

    k_detect   <<<1, 64, 0, stream>>>((const int*)ei, flag);
    k_zero     <<<(nbuck + 255) / 256, 256, 0, stream>>>(bcnt, nbuck);
    k_bhist    <<<nbB, 256, 0, stream>>>(ei, flag, bcnt, E, nbuck);
    k_bscan    <<<1, 1024, 0, stream>>>(bcnt, bbase, bcur, nbuck, E, row_ptr, n);
    k_bscatter <<<nbB, 256, 0, stream>>>(ei, flag, bcur, pair, E, nbuck);
    k_bsort2   <<<nbuck, 256, 0, stream>>>(pair, bbase, row_ptr, dinv, csr_col, n);
    k_gemm1    <<<nb, 256, 0, stream>>>(x, W1, dinv, hn, n);
    k_agg1     <<<nb4, 256, 0, stream>>>(hn, row_ptr, csr_col, dinv, b1, u, n);
    k_agg2f    <<<nb4, 256, 0, stream>>>(u, row_ptr, csr_col, dinv, W2, b2, out, n);
}